// Round 5
// baseline (197.746 us; speedup 1.0000x reference)
//
#include <hip/hip_runtime.h>
#include <hip/hip_bf16.h>

// Pipeline (R12): wtrans -> fused(gemm||fill2) -> bucket_gather(column-split)
//  - R11 post-mortem: gather time tracks FETCH bytes at a pinned ~3.4TB/s
//    across 3 configs (occupancy moves, rate doesn't) -> byte-bound; gather
//    frozen at R11 config (62us, 158MB).
//  - R12: gemm tile 64->128 rows/block. Grid 1819->1038 blocks @ 2/CU =
//    2.03 scheduling rounds (was 3.55); WT staged once per 128 rows; 16
//    MFMA/wave. LDS 52->68KB (still 2 blocks/CU, threads were the cap).

#define D 128
#define NB_SHIFT 6
#define BNODES 64
#define MAXB 2048            // >= nb = 1563
#define CAPB 1408            // mean 1023 + 12 sigma
#define RPT 6                // ceil(CAPB/256)
#define XSTR 136             // LDS row stride (ushorts): 272B = 4-bank shift/row
#define NFILL 256            // fill2 blocks in fused kernel (1 per CU)
#define GROWS 128            // gemm rows per block

using bf16x8 = __attribute__((ext_vector_type(8))) short;
using f32x4  = __attribute__((ext_vector_type(4))) float;

__device__ inline unsigned short f2bf(float f) {
    unsigned u = __float_as_uint(f);
    u += 0x7fffu + ((u >> 16) & 1u);
    return (unsigned short)(u >> 16);
}
__device__ inline float bflo(unsigned w) { return __uint_as_float(w << 16); }
__device__ inline float bfhi(unsigned w) { return __uint_as_float(w & 0xffff0000u); }

// ---------------- wtrans: WT[n][k] = bf16(W[k][n]); also zeroes cursor ----------------
__global__ __launch_bounds__(256) void wtrans(const float* __restrict__ W,
                                              unsigned short* __restrict__ WT,
                                              int* cursor, int nb) {
    const int t = threadIdx.x, b = blockIdx.x;   // 8 blocks
    const int n  = (b << 4) | (t & 15);
    const int k0 = (t >> 4) << 3;
#pragma unroll
    for (int k = k0; k < k0 + 8; ++k)
        WT[n * D + k] = f2bf(W[k * D + n]);
    if (b == 0)
        for (int i = t; i < nb; i += 256) cursor[i] = 0;
}

// ---------------- fused kernel: fill2 path + gemm path ----------------
// LDS union: gemm needs Xl(34.8KB)+Wl(34.8KB)=69.6KB; fill2 needs 16KB.
#define SMEM_BYTES (GROWS * XSTR * 2 + 128 * XSTR * 2)

__device__ void gemm_path(const float* __restrict__ X,
                          const unsigned short* __restrict__ WT,
                          unsigned short* __restrict__ S,
                          int nRows, int blk, char* smem) {
    unsigned short* Xl = (unsigned short*)smem;                       // [128][XSTR]
    unsigned short* Wl = (unsigned short*)(smem + GROWS * XSTR * 2);  // [128][XSTR]

    const int t = threadIdx.x;                 // 0..1023
    const int row0 = blk * GROWS;

    // stage WT (16384 ushort = 2048 uint4), coalesced, 2 iters
    const uint4* WT4 = (const uint4*)WT;
    uint4* Wl4 = (uint4*)Wl;
#pragma unroll
    for (int i = t; i < 2048; i += 1024) {
        int n = i >> 4, kc8 = i & 15;
        Wl4[n * (XSTR / 8) + kc8] = WT4[i];
    }

    // stage X tile fp32 -> bf16 (4096 float4), 4 iters
    const float4* X4 = (const float4*)X;
    ushort4* Xl4 = (ushort4*)Xl;
#pragma unroll
    for (int i = t; i < 4096; i += 1024) {
        int r = i >> 5, c = i & 31;
        int gr = row0 + r;
        float4 v = make_float4(0.f, 0.f, 0.f, 0.f);
        if (gr < nRows) v = X4[(size_t)gr * 32 + c];
        ushort4 p;
        p.x = f2bf(v.x); p.y = f2bf(v.y); p.z = f2bf(v.z); p.w = f2bf(v.w);
        Xl4[r * (XSTR / 4) + c] = p;
    }
    __syncthreads();

    // 16 waves: wave w -> row tile (w&7)*16..+15, nt quad (w>>3)*4..+3
    const int wv = t >> 6, lane = t & 63;
    const int m = lane & 15, quad = lane >> 4;
    const int m0  = (wv & 7) << 4;
    const int nt0 = (wv >> 3) << 2;

    f32x4 acc[4];
    f32x4 z = {0.f, 0.f, 0.f, 0.f};
#pragma unroll
    for (int nt = 0; nt < 4; ++nt) acc[nt] = z;

#pragma unroll
    for (int kc = 0; kc < 4; ++kc) {
        bf16x8 a = *(const bf16x8*)(Xl + (m0 + m) * XSTR + kc * 32 + quad * 8);
#pragma unroll
        for (int nt = 0; nt < 4; ++nt) {
            bf16x8 b = *(const bf16x8*)(Wl + ((nt0 + nt) * 16 + m) * XSTR + kc * 32 + quad * 8);
            acc[nt] = __builtin_amdgcn_mfma_f32_16x16x32_bf16(a, b, acc[nt], 0, 0, 0);
        }
    }

    // D[row = quad*4+r][col = (nt0+nt)*16+m]
#pragma unroll
    for (int nt = 0; nt < 4; ++nt) {
#pragma unroll
        for (int r = 0; r < 4; ++r) {
            int gr = row0 + m0 + quad * 4 + r;
            if (gr < nRows)
                S[(size_t)gr * D + (nt0 + nt) * 16 + m] = f2bf(acc[nt][r]);
        }
    }
}

__device__ void fill2_path(const int* __restrict__ src,
                           const int* __restrict__ dst,
                           const float* __restrict__ vals,
                           int* gcursor, int2* __restrict__ epk,
                           int E, int nb, int blk, char* smem) {
    int* h   = (int*)smem;                  // [MAXB]
    int* cur = (int*)(smem + MAXB * 4);     // [MAXB]
    const int t = threadIdx.x;              // 0..1023
    for (int i = t; i < nb; i += 1024) h[i] = 0;
    __syncthreads();

    int chunk = (E + NFILL - 1) / NFILL;
    chunk = (chunk + 3) & ~3;                     // keep int4 alignment
    const int s0 = min(E, blk * chunk);
    const int s1 = min(E, s0 + chunk);
    const int vend = s0 + ((s1 - s0) & ~3);       // int4 region

    // pass 1: histogram, int4 loads (4 edges/thread/iter)
    int e = s0 + (t << 2);
    for (; e + 4 <= vend; e += 4096) {
        int4 d = *(const int4*)(dst + e);
        atomicAdd(&h[d.x >> NB_SHIFT], 1);
        atomicAdd(&h[d.y >> NB_SHIFT], 1);
        atomicAdd(&h[d.z >> NB_SHIFT], 1);
        atomicAdd(&h[d.w >> NB_SHIFT], 1);
    }
    for (e = vend + t; e < s1; e += 1024) atomicAdd(&h[dst[e] >> NB_SHIFT], 1);
    __syncthreads();

    // reserve per-WG sub-window inside each bucket's fixed window
    for (int i = t; i < nb; i += 1024) {
        int c = h[i];
        cur[i] = c ? (i * CAPB + atomicAdd(&gcursor[i], c)) : 0;
    }
    __syncthreads();

    // pass 2: scatter
    e = s0 + (t << 2);
    for (; e + 4 <= vend; e += 4096) {
        int4   d = *(const int4*)(dst + e);
        int4   s = *(const int4*)(src + e);
        float4 v = *(const float4*)(vals + e);
        int p0 = atomicAdd(&cur[d.x >> NB_SHIFT], 1);
        int p1 = atomicAdd(&cur[d.y >> NB_SHIFT], 1);
        int p2 = atomicAdd(&cur[d.z >> NB_SHIFT], 1);
        int p3 = atomicAdd(&cur[d.w >> NB_SHIFT], 1);
        epk[p0] = make_int2(s.x | ((d.x & (BNODES - 1)) << 20), __float_as_int(v.x));
        epk[p1] = make_int2(s.y | ((d.y & (BNODES - 1)) << 20), __float_as_int(v.y));
        epk[p2] = make_int2(s.z | ((d.z & (BNODES - 1)) << 20), __float_as_int(v.z));
        epk[p3] = make_int2(s.w | ((d.w & (BNODES - 1)) << 20), __float_as_int(v.w));
    }
    for (e = vend + t; e < s1; e += 1024) {
        int d = dst[e];
        int pos = atomicAdd(&cur[d >> NB_SHIFT], 1);
        epk[pos] = make_int2(src[e] | ((d & (BNODES - 1)) << 20), __float_as_int(vals[e]));
    }
}

__global__ __launch_bounds__(1024, 8) void fused_pre(const float* __restrict__ X,
                                                     const unsigned short* __restrict__ WT,
                                                     unsigned short* __restrict__ S,
                                                     int nRows,
                                                     const int* __restrict__ src,
                                                     const int* __restrict__ dst,
                                                     const float* __restrict__ vals,
                                                     int* gcursor, int2* __restrict__ epk,
                                                     int E, int nb) {
    __shared__ char smem[SMEM_BYTES];
    const int bid = blockIdx.x;
    if (bid < NFILL)
        fill2_path(src, dst, vals, gcursor, epk, E, nb, bid, smem);
    else
        gemm_path(X, WT, S, nRows, bid - NFILL, smem);
}

// ---------------- bucket_gather: column-split, 2 blocks per bucket ----------------
// UNCHANGED from R11 (62us, byte-bound at ~3.4TB/s). Block 2b+h: bucket b,
// output cols h*64..h*64+63; 3126 blocks of 256 thr; 8 blocks/CU.
#define ACC8(e, mm) { float v = __int_as_float(e.y);                         \
    a[0] = fmaf(v, bflo(mm.x), a[0]); a[1] = fmaf(v, bfhi(mm.x), a[1]);      \
    a[2] = fmaf(v, bflo(mm.y), a[2]); a[3] = fmaf(v, bfhi(mm.y), a[3]);      \
    a[4] = fmaf(v, bflo(mm.z), a[4]); a[5] = fmaf(v, bfhi(mm.z), a[5]);      \
    a[6] = fmaf(v, bflo(mm.w), a[6]); a[7] = fmaf(v, bfhi(mm.w), a[7]); }

__global__ __launch_bounds__(256, 8) void bucket_gather(const unsigned short* __restrict__ support,
                                                        const int* __restrict__ gcursor,
                                                        const int2* __restrict__ epk,
                                                        float* __restrict__ out, int N) {
    __shared__ int2 se[CAPB];       // 11.3 KB
    __shared__ int  hist[BNODES];
    __shared__ int  rows[BNODES];
    __shared__ int  cur[BNODES];

    const int t    = threadIdx.x;
    const int b    = blockIdx.x >> 1;     // bucket
    const int half = blockIdx.x & 1;      // column half (0: cols 0-63, 1: 64-127)
    const int cnt  = min(gcursor[b], CAPB);
    const int beg  = b * CAPB;

    if (t < BNODES) hist[t] = 0;
    __syncthreads();

    // stage this thread's edges in registers: ONE global epk read total
    int2 r[RPT];
#pragma unroll
    for (int i = 0; i < RPT; ++i) {
        int idx = t + (i << 8);
        if (idx < cnt) r[i] = epk[beg + idx];
    }
#pragma unroll
    for (int i = 0; i < RPT; ++i) {
        int idx = t + (i << 8);
        if (idx < cnt) atomicAdd(&hist[(r[i].x >> 20) & (BNODES - 1)], 1);
    }
    __syncthreads();

    // Hillis-Steele inclusive scan of 64 counters
    if (t < BNODES) rows[t] = hist[t];
    __syncthreads();
#pragma unroll
    for (int off = 1; off < BNODES; off <<= 1) {
        int v = 0;
        if (t < BNODES && t >= off) v = rows[t - off];
        __syncthreads();
        if (t < BNODES && t >= off) rows[t] += v;
        __syncthreads();
    }
    if (t < BNODES) cur[t] = rows[t] - hist[t];
    __syncthreads();

    // scatter registers into sorted LDS order
#pragma unroll
    for (int i = 0; i < RPT; ++i) {
        int idx = t + (i << 8);
        if (idx < cnt) {
            int pos = atomicAdd(&cur[(r[i].x >> 20) & (BNODES - 1)], 1);
            se[pos] = r[i];
        }
    }
    __syncthreads();

    // per-node accumulation: group g (8 lanes) handles nodes g, g+32
    const int g = t >> 3, lane = t & 7;
    const int node0 = b << NB_SHIFT;
    const int colbase = half << 3;               // uint4 offset within support row
    const uint4* S4 = (const uint4*)support;
    float4* o4 = (float4*)out;

#pragma unroll
    for (int nn = g; nn < BNODES; nn += 32) {
        const int send = rows[nn];
        const int sbeg = send - hist[nn];

        float a[8];
#pragma unroll
        for (int k = 0; k < 8; ++k) a[k] = 0.f;

        int j = sbeg;
        for (; j + 4 <= send; j += 4) {          // 4 outstanding 128 B gathers
            int2 e0 = se[j], e1 = se[j + 1], e2 = se[j + 2], e3 = se[j + 3];
            uint4 m0 = S4[(size_t)(e0.x & 0xFFFFF) * 16 + colbase + lane];
            uint4 m1 = S4[(size_t)(e1.x & 0xFFFFF) * 16 + colbase + lane];
            uint4 m2 = S4[(size_t)(e2.x & 0xFFFFF) * 16 + colbase + lane];
            uint4 m3 = S4[(size_t)(e3.x & 0xFFFFF) * 16 + colbase + lane];
            ACC8(e0, m0); ACC8(e1, m1); ACC8(e2, m2); ACC8(e3, m3);
        }
        for (; j < send; ++j) {
            int2 e0 = se[j];
            uint4 m0 = S4[(size_t)(e0.x & 0xFFFFF) * 16 + colbase + lane];
            ACC8(e0, m0);
        }

        const int gn = node0 + nn;
        if (gn < N) {
            size_t base = (size_t)gn * 32 + (half << 4) + 2 * lane;
            float4 lo = make_float4(fmaxf(a[0], 0.f), fmaxf(a[1], 0.f),
                                    fmaxf(a[2], 0.f), fmaxf(a[3], 0.f));
            float4 hi = make_float4(fmaxf(a[4], 0.f), fmaxf(a[5], 0.f),
                                    fmaxf(a[6], 0.f), fmaxf(a[7], 0.f));
            o4[base]     = lo;
            o4[base + 1] = hi;
        }
    }
}

extern "C" void kernel_launch(void* const* d_in, const int* in_sizes, int n_in,
                              void* d_out, int out_size, void* d_ws, size_t ws_size,
                              hipStream_t stream) {
    const float* X    = (const float*)d_in[0];
    const float* W    = (const float*)d_in[1];
    const float* vals = (const float*)d_in[2];
    const int*   src  = (const int*)d_in[3];
    const int*   dst  = (const int*)d_in[4];
    float*       out  = (float*)d_out;

    const int N  = in_sizes[0] / D;
    const int E  = in_sizes[2];
    const int nb = (N + BNODES - 1) / BNODES;   // 1563

    size_t off = 0;
    auto take = [&](size_t bytes) {
        size_t p = off;
        off = (off + bytes + 255) & ~(size_t)255;
        return p;
    };
    char* ws = (char*)d_ws;
    size_t o_support = take((size_t)N * D * sizeof(unsigned short));
    size_t o_wt      = take((size_t)D * D * sizeof(unsigned short));
    size_t o_cursor  = take((size_t)nb * sizeof(int));
    size_t o_epk     = take(((size_t)nb * CAPB + 1024) * sizeof(int2));
    (void)ws_size;

    unsigned short* support = (unsigned short*)(ws + o_support);
    unsigned short* WT      = (unsigned short*)(ws + o_wt);
    int*  cursor = (int*)(ws + o_cursor);
    int2* epk    = (int2*)(ws + o_epk);

    // 1) WT = bf16(W^T); zero bucket cursors
    wtrans<<<8, 256, 0, stream>>>(W, WT, cursor, nb);

    // 2) fused: fill2 (blocks 0..255) || gemm (blocks 256..256+nbG-1)
    const int nbG = (N + GROWS - 1) / GROWS;    // 782
    fused_pre<<<NFILL + nbG, 1024, 0, stream>>>(X, WT, support, N,
                                                src, dst, vals, cursor, epk, E, nb);

    // 3) per-bucket sort + gather + ReLU (2 blocks per bucket, column-split)
    bucket_gather<<<2 * nb, 256, 0, stream>>>(support, cursor, epk, out, N);
}